// Round 2
// baseline (25.417 us; speedup 1.0000x reference)
//
#include <hip/hip_runtime.h>

#define NGT 64
#define NUM_CLASSES_F 80.0f
#define INF_F 100000000.0f
#define RADIUS_F 1.5f

// Setup: per-box derived table in d_ws: {x1,y1,x2,y2, ccx,ccy,area,clsf} x (B*G)
__global__ void fcos_setup_kernel(const float* __restrict__ gt_boxes,
                                  const int* __restrict__ gt_classes,
                                  float* __restrict__ tb, int BG)
{
    const int t = blockIdx.x * blockDim.x + threadIdx.x;
    if (t >= BG) return;
    const float4 bx = reinterpret_cast<const float4*>(gt_boxes)[t];
    float4* e = reinterpret_cast<float4*>(tb + (size_t)t * 8);
    e[0] = bx;
    e[1] = make_float4((bx.x + bx.z) * 0.5f,
                       (bx.y + bx.w) * 0.5f,
                       (bx.z - bx.x) * (bx.w - bx.y),
                       (float)gt_classes[t]);
}

__global__ __launch_bounds__(256) void fcos_match_kernel(
    const float* __restrict__ locations,      // (L,2)
    const float* __restrict__ strides_per_loc,// (L,)
    const float* __restrict__ soi,            // (L,2)
    const float* __restrict__ anchors,        // (L,4)
    const float* __restrict__ tb,             // (B*G, 8) derived table
    float* __restrict__ out,                  // cls (B*L) | reg (B*L*4) | deltas (B*L*4)
    int L, int B)
{
    const int b = blockIdx.y;
    const int i = blockIdx.x * blockDim.x + threadIdx.x;
    if (i >= L) return;

    const float2 xy   = reinterpret_cast<const float2*>(locations)[i];
    const float  x    = xy.x, y = xy.y;
    const float  rad  = strides_per_loc[i] * RADIUS_F;
    const float2 lohi = reinterpret_cast<const float2*>(soi)[i];

    // Wave-uniform base: blockIdx.y * 512 floats. All tb[] reads below have
    // uniform addresses -> scalar loads (s_load_dwordx4), SGPR operands.
    const float* __restrict__ bt = tb + (size_t)b * NGT * 8;

    float minv = INF_F;
    int   ind  = 0;

    #pragma unroll
    for (int j = 0; j < NGT; ++j) {
        const float bx0  = bt[j * 8 + 0];
        const float by0  = bt[j * 8 + 1];
        const float bx1  = bt[j * 8 + 2];
        const float by1  = bt[j * 8 + 3];
        const float ccx  = bt[j * 8 + 4];
        const float ccy  = bt[j * 8 + 5];
        const float area = bt[j * 8 + 6];

        const float l  = x - bx0;
        const float t  = y - by0;
        const float r  = bx1 - x;
        const float bb = by1 - y;
        const float mx = fmaxf(fmaxf(l, t), fmaxf(r, bb));      // max3 + max

        const float xmin = fmaxf(ccx - rad, bx0);
        const float ymin = fmaxf(ccy - rad, by0);
        const float xmax = fminf(ccx + rad, bx1);
        const float ymax = fminf(ccy + rad, by1);
        const float cb   = fminf(fminf(x - xmin, y - ymin),
                                 fminf(xmax - x, ymax - y));    // min3 + min

        const float g = fminf(mx - lohi.x, lohi.y - mx);        // >=lo && <=hi
        const bool valid = (cb > 0.0f) && (g >= 0.0f);
        const float v = valid ? area : INF_F;
        if (v < minv) { minv = v; ind = j; }   // strict < -> first-occurrence argmin
    }

    // Epilogue: ind is per-thread -> vector loads (L2-hit, tiny table).
    const float4* me = reinterpret_cast<const float4*>(bt + ind * 8);
    const float4 mb = me[0];   // x1,y1,x2,y2
    const float4 md = me[1];   // ccx,ccy,area,clsf

    // cls
    out[(size_t)b * L + i] = (minv == INF_F) ? NUM_CLASSES_F : md.w;

    // reg targets (16B-aligned float4 store)
    const size_t o4 = (size_t)b * L + i;
    float4* reg4 = reinterpret_cast<float4*>(out + (size_t)B * L) + o4;
    *reg4 = make_float4(x - mb.x, y - mb.y, mb.z - x, mb.w - y);

    // deltas
    const float4 an = reinterpret_cast<const float4*>(anchors)[i];
    const float aw  = an.z - an.x;
    const float ah  = an.w - an.y;
    const float acx = an.x + 0.5f * aw;
    const float acy = an.y + 0.5f * ah;
    const float gw  = mb.z - mb.x;
    const float gh  = mb.w - mb.y;
    const float gcx = mb.x + 0.5f * gw;
    const float gcy = mb.y + 0.5f * gh;

    float4* del4 = reinterpret_cast<float4*>(out + (size_t)B * L * 5) + o4;
    *del4 = make_float4((gcx - acx) / aw, (gcy - acy) / ah,
                        logf(gw / aw), logf(gh / ah));
}

extern "C" void kernel_launch(void* const* d_in, const int* in_sizes, int n_in,
                              void* d_out, int out_size, void* d_ws, size_t ws_size,
                              hipStream_t stream) {
    const float* locations = (const float*)d_in[0];
    const float* strides   = (const float*)d_in[1];
    const float* soi       = (const float*)d_in[2];
    const float* anchors   = (const float*)d_in[3];
    const float* gt_boxes  = (const float*)d_in[4];
    const int*   gt_cls    = (const int*)d_in[5];
    float* out = (float*)d_out;
    float* tb  = (float*)d_ws;                 // (B*G)*8 floats = 16 KB

    const int L  = in_sizes[1];                // strides_per_loc: L elements
    const int BG = in_sizes[5];                // gt_classes: B*G elements
    const int B  = BG / NGT;

    fcos_setup_kernel<<<(BG + 255) / 256, 256, 0, stream>>>(gt_boxes, gt_cls, tb, BG);

    dim3 grid((L + 255) / 256, B);
    fcos_match_kernel<<<grid, dim3(256), 0, stream>>>(locations, strides, soi, anchors,
                                                      tb, out, L, B);
}

// Round 3
// 21.133 us; speedup vs baseline: 1.2028x; 1.2028x over previous
//
#include <hip/hip_runtime.h>

#define NGT 64
#define NUM_CLASSES_F 80.0f
#define INF_F 100000000.0f
#define RADIUS_F 1.5f

static __device__ __forceinline__ float readlane_f(float v, int lane) {
    return __int_as_float(__builtin_amdgcn_readlane(__float_as_int(v), lane));
}

__global__ __launch_bounds__(256) void fcos_match_kernel(
    const float* __restrict__ locations,      // (L,2)
    const float* __restrict__ strides_per_loc,// (L,)
    const float* __restrict__ soi,            // (L,2)
    const float* __restrict__ anchors,        // (L,4)
    const float* __restrict__ gt_boxes,       // (B,G,4)
    const int*   __restrict__ gt_classes,     // (B,G)
    float* __restrict__ out,                  // cls (B*L) | reg (B*L*4) | deltas (B*L*4)
    int L, int B)
{
    const int b   = blockIdx.y;
    const int tid = blockIdx.x * blockDim.x + threadIdx.x;
    const int i   = (tid < L) ? tid : (L - 1);     // clamp; stores predicated later
    const int lane = threadIdx.x & 63;

    // Lane j owns box j of image b: one coalesced float4 + one int load per lane.
    const float4 mybx = reinterpret_cast<const float4*>(gt_boxes)[b * NGT + lane];
    const float my_x1 = mybx.x, my_y1 = mybx.y, my_x2 = mybx.z, my_y2 = mybx.w;
    const float my_ccx  = (mybx.x + mybx.z) * 0.5f;
    const float my_ccy  = (mybx.y + mybx.w) * 0.5f;
    const float my_area = (mybx.z - mybx.x) * (mybx.w - mybx.y);
    const float my_clsf = (float)gt_classes[b * NGT + lane];

    const float2 xy   = reinterpret_cast<const float2*>(locations)[i];
    const float  x    = xy.x, y = xy.y;
    const float  rad  = strides_per_loc[i] * RADIUS_F;
    const float2 lohi = reinterpret_cast<const float2*>(soi)[i];
    const float  lo   = lohi.x, hi = lohi.y;

    float minv = INF_F;
    int   ind  = 0;

    #pragma unroll
    for (int j = 0; j < NGT; ++j) {
        // Broadcast box j from lane j: v_readlane -> SGPR (no LDS, no VMEM).
        const float bx0  = readlane_f(my_x1, j);
        const float by0  = readlane_f(my_y1, j);
        const float bx1  = readlane_f(my_x2, j);
        const float by1  = readlane_f(my_y2, j);
        const float ccx  = readlane_f(my_ccx, j);
        const float ccy  = readlane_f(my_ccy, j);
        const float area = readlane_f(my_area, j);

        const float l  = x - bx0;
        const float t  = y - by0;
        const float r  = bx1 - x;
        const float bb = by1 - y;
        const float mx = fmaxf(fmaxf(l, t), fmaxf(r, bb));      // max3 + max

        const float xmin = fmaxf(ccx - rad, bx0);
        const float ymin = fmaxf(ccy - rad, by0);
        const float xmax = fminf(ccx + rad, bx1);
        const float ymax = fminf(ccy + rad, by1);
        const float cb   = fminf(fminf(x - xmin, y - ymin),
                                 fminf(xmax - x, ymax - y));    // min3 + min

        const float g = fminf(mx - lo, hi - mx);                // >=lo && <=hi
        const float v = ((cb > 0.0f) && (g >= 0.0f)) ? area : INF_F;
        if (v < minv) { minv = v; ind = j; }   // strict < -> first-occurrence argmin
    }

    // Epilogue: gather box[ind] across lanes (divergent index -> ds_bpermute).
    const float mbx0 = __shfl(my_x1, ind);
    const float mby0 = __shfl(my_y1, ind);
    const float mbx1 = __shfl(my_x2, ind);
    const float mby1 = __shfl(my_y2, ind);
    const float mcls = __shfl(my_clsf, ind);

    if (tid >= L) return;

    // cls
    out[(size_t)b * L + i] = (minv == INF_F) ? NUM_CLASSES_F : mcls;

    // reg targets (16B-aligned float4 store)
    const size_t o4 = (size_t)b * L + i;
    float4* reg4 = reinterpret_cast<float4*>(out + (size_t)B * L) + o4;
    *reg4 = make_float4(x - mbx0, y - mby0, mbx1 - x, mby1 - y);

    // deltas
    const float4 an = reinterpret_cast<const float4*>(anchors)[i];
    const float aw  = an.z - an.x;
    const float ah  = an.w - an.y;
    const float acx = an.x + 0.5f * aw;
    const float acy = an.y + 0.5f * ah;
    const float gw  = mbx1 - mbx0;
    const float gh  = mby1 - mby0;
    const float gcx = mbx0 + 0.5f * gw;
    const float gcy = mby0 + 0.5f * gh;

    float4* del4 = reinterpret_cast<float4*>(out + (size_t)B * L * 5) + o4;
    *del4 = make_float4((gcx - acx) / aw, (gcy - acy) / ah,
                        logf(gw / aw), logf(gh / ah));
}

extern "C" void kernel_launch(void* const* d_in, const int* in_sizes, int n_in,
                              void* d_out, int out_size, void* d_ws, size_t ws_size,
                              hipStream_t stream) {
    const float* locations = (const float*)d_in[0];
    const float* strides   = (const float*)d_in[1];
    const float* soi       = (const float*)d_in[2];
    const float* anchors   = (const float*)d_in[3];
    const float* gt_boxes  = (const float*)d_in[4];
    const int*   gt_cls    = (const int*)d_in[5];
    float* out = (float*)d_out;

    const int L = in_sizes[1];            // strides_per_loc has L elements
    const int B = in_sizes[5] / NGT;      // gt_classes has B*G elements

    dim3 grid((L + 255) / 256, B);
    fcos_match_kernel<<<grid, dim3(256), 0, stream>>>(locations, strides, soi, anchors,
                                                      gt_boxes, gt_cls, out, L, B);
}